// Round 12
// baseline (1390.707 us; speedup 1.0000x reference)
//
#include <hip/hip_runtime.h>
#include <hip/hip_bf16.h>

typedef __hip_bfloat16 bf16;
typedef __attribute__((ext_vector_type(4))) float f32x4;
typedef __attribute__((ext_vector_type(8))) short s16x8;

#define N_TOK 4096   // B*S
#define Dm    512
#define Fm    2048
#define Em    8

__device__ __forceinline__ float bf2f(bf16 v) { return __bfloat162float(v); }
__device__ __forceinline__ bf16  f2bf(float f) { return __float2bfloat16(f); }

// async global->LDS, 16B per lane; LDS dest is wave-uniform base + lane*16
#define GL16(g, l)                                                              \
  __builtin_amdgcn_global_load_lds(                                             \
      (const __attribute__((address_space(1))) void*)(g),                       \
      (__attribute__((address_space(3))) void*)(l), 16, 0, 0)

#define BAR()                                   \
  do {                                          \
    __builtin_amdgcn_s_barrier();               \
    asm volatile("" ::: "memory");              \
  } while (0)

// ---------------- fp32 -> bf16 flat convert ----------------------------------
__global__ void cvt_f32_bf16(const float* __restrict__ in, bf16* __restrict__ out, int n4) {
  int i = blockIdx.x * 256 + threadIdx.x;
  if (i >= n4) return;
  float4 v = reinterpret_cast<const float4*>(in)[i];
  bf16 tmp[4] = {f2bf(v.x), f2bf(v.y), f2bf(v.z), f2bf(v.w)};
  __builtin_memcpy(out + (size_t)i * 4, tmp, 8);
}

// ---------------- fp32 [R][C] -> bf16 [C][R] tiled transpose-convert ---------
__global__ void transpose_cvt(const float* __restrict__ in, bf16* __restrict__ out,
                              int R, int C, long inb, long outb) {
  in  += (long)blockIdx.z * inb;
  out += (long)blockIdx.z * outb;
  __shared__ float t[32][33];
  int tx = threadIdx.x & 31, ty = threadIdx.x >> 5;
  int c0 = blockIdx.x * 32, r0 = blockIdx.y * 32;
#pragma unroll
  for (int i = 0; i < 32; i += 8)
    t[ty + i][tx] = in[(long)(r0 + ty + i) * C + c0 + tx];
  __syncthreads();
#pragma unroll
  for (int i = 0; i < 32; i += 8)
    out[(long)(c0 + ty + i) * R + r0 + tx] = f2bf(t[tx][ty + i]);
}

// ====== 256x256 BK=32 bf16 GEMM, 3-buffer 2-tile-deep pipeline (r12) =========
// C = A @ Bt^T (+bias[, relu]).  A:[M][K] lda, Bt:[N][K] ldb, C row-major ldc.
// 8 waves (2Mx4N), wave tile 128x64 (15.6 B LDS-read / KFLOP — half of 128²'s),
// 3 LDS tile-buffers (96 KB), prefetch depth 2 tiles (wait-to-issue = 4 phases
// >= ~600cy, covers L2 latency — r8's 1-phase distance was the stall).
// Sync per K-tile: ONE s_waitcnt vmcnt(4) + ONE barrier. NO sched_barrier
// (m141/r2: order-pinning costs ~40%). 2 phases/tile, 16 MFMA each, setprio.
// Hazards (audited): wait-then-barrier => all waves' t-loads retired before
// any wave reads t; staging t+2 clobbers buf(t-1) only after barrier(t), by
// which point every wave finished t-1's phases. Swizzle both sides (#21):
// LDS[row][p] holds global k-chunk p ^ ((row>>1)&3) (inverse-swizzled global
// source, linear LDS dest); ds_read phys slot = q ^ ((r>>1)&3) -> 2-way max
// (free, m136). Swapped MFMA operands (verified r8-r10): acc[m][n][r] ->
// C[bm+wm*128+(m>>2)*64+(m&3)*16+la][bn+wn*64+n*16+q*4+r], packed stores.
template <bool RELU, bool OUT_BF16>
__global__ void gemm3p(
    const bf16* __restrict__ A, const bf16* __restrict__ Bt, void* __restrict__ Cout,
    const float* __restrict__ bias, int K, int lda, int ldb, int ldc,
    long abs_, long bbs, long cbs, long biasbs) {
  extern __shared__ bf16 lds[];  // 3 bufs x (8192 A + 8192 B) bf16 = 96 KB

  int e  = blockIdx.z;
  int bm = blockIdx.x * 256, bn = blockIdx.y * 256;

  A    += (long)e * abs_;
  Bt   += (long)e * bbs;
  bias += (long)e * biasbs;
  long coff = (long)e * cbs;

  int tid = threadIdx.x, wv = tid >> 6, lane = tid & 63;
  int wm = wv >> 2, wn = wv & 3;  // 2x4 wave grid, 128x64 per wave
  int la = lane & 15, q = lane >> 4;

  const bf16* Ab = A + (long)bm * lda;
  const bf16* Bb = Bt + (long)bn * ldb;
  int nt = K >> 5;  // BK = 32

  // staging: per thread 2 A-chunks + 2 B-chunks (16B each) per tile.
  // chunk c = j*512 + tid -> row = c>>2 (j=1: +128), phys slot p = tid&3,
  // logical (global) slot = p ^ ((row>>1)&3)  [same for j=0/1: +128 keeps it]
  int srow = tid >> 2;
  int ls   = (tid & 3) ^ ((srow >> 1) & 3);
  long aoff0 = (long)srow * lda + ls * 8, aoff1 = aoff0 + (long)128 * lda;
  long boff0 = (long)srow * ldb + ls * 8, boff1 = boff0 + (long)128 * ldb;
  int dst0 = (wv * 64) * 8, dst1 = (512 + wv * 64) * 8;  // wave-uniform bases

  auto stageA = [&](int t) {
    if (t >= nt) return;
    bf16* buf = lds + (t % 3) * 16384;
    int k0 = t << 5;
    GL16(Ab + aoff0 + k0, buf + dst0);
    GL16(Ab + aoff1 + k0, buf + dst1);
  };
  auto stageB = [&](int t) {
    if (t >= nt) return;
    bf16* buf = lds + (t % 3) * 16384 + 8192;
    int k0 = t << 5;
    GL16(Bb + boff0 + k0, buf + dst0);
    GL16(Bb + boff1 + k0, buf + dst1);
  };

  f32x4 acc[8][4] = {};
  s16x8 af[4], bfr[4];

  // prologue: tiles 0 and 1 fully in flight (8 loads/thread outstanding)
  stageA(0); stageB(0);
  stageA(1); stageB(1);

  for (int t = 0; t < nt; ++t) {
    if (t + 1 < nt) asm volatile("s_waitcnt vmcnt(4)" ::: "memory");
    else            asm volatile("s_waitcnt vmcnt(0)" ::: "memory");
    BAR();  // all waves' tile-t loads retired & visible
    const bf16* Abuf = lds + (t % 3) * 16384;
    const bf16* Bbuf = Abuf + 8192;
    // ---- phase 1: m-half 0 ----
#pragma unroll
    for (int m = 0; m < 4; ++m) {
      int r = wm * 128 + m * 16 + la;
      af[m] = *reinterpret_cast<const s16x8*>(Abuf + r * 32 + ((q ^ ((r >> 1) & 3)) * 8));
    }
#pragma unroll
    for (int n = 0; n < 4; ++n) {
      int r = wn * 64 + n * 16 + la;
      bfr[n] = *reinterpret_cast<const s16x8*>(Bbuf + r * 32 + ((q ^ ((r >> 1) & 3)) * 8));
    }
    stageA(t + 2);
    __builtin_amdgcn_s_setprio(1);
#pragma unroll
    for (int m = 0; m < 4; ++m)
#pragma unroll
      for (int n = 0; n < 4; ++n)
        acc[m][n] = __builtin_amdgcn_mfma_f32_16x16x32_bf16(bfr[n], af[m], acc[m][n], 0, 0, 0);
    __builtin_amdgcn_s_setprio(0);
    // ---- phase 2: m-half 1 (B frags reused from registers) ----
#pragma unroll
    for (int m = 0; m < 4; ++m) {
      int r = wm * 128 + 64 + m * 16 + la;
      af[m] = *reinterpret_cast<const s16x8*>(Abuf + r * 32 + ((q ^ ((r >> 1) & 3)) * 8));
    }
    stageB(t + 2);
    __builtin_amdgcn_s_setprio(1);
#pragma unroll
    for (int m = 0; m < 4; ++m)
#pragma unroll
      for (int n = 0; n < 4; ++n)
        acc[4 + m][n] = __builtin_amdgcn_mfma_f32_16x16x32_bf16(bfr[n], af[m], acc[4 + m][n], 0, 0, 0);
    __builtin_amdgcn_s_setprio(0);
  }

  // epilogue
#pragma unroll
  for (int m = 0; m < 8; ++m) {
    int gm = bm + wm * 128 + (m >> 2) * 64 + (m & 3) * 16 + la;
#pragma unroll
    for (int n = 0; n < 4; ++n) {
      int gn = bn + wn * 64 + n * 16 + q * 4;
      float4 b4 = *reinterpret_cast<const float4*>(bias + gn);
      float v0 = acc[m][n][0] + b4.x, v1 = acc[m][n][1] + b4.y;
      float v2 = acc[m][n][2] + b4.z, v3 = acc[m][n][3] + b4.w;
      if (RELU) {
        v0 = fmaxf(v0, 0.f); v1 = fmaxf(v1, 0.f);
        v2 = fmaxf(v2, 0.f); v3 = fmaxf(v3, 0.f);
      }
      long idx = coff + (long)gm * ldc + gn;
      if (OUT_BF16) {
        bf16 tmp[4] = {f2bf(v0), f2bf(v1), f2bf(v2), f2bf(v3)};
        __builtin_memcpy((bf16*)Cout + idx, tmp, 8);
      } else {
        float tmp[4] = {v0, v1, v2, v3};
        __builtin_memcpy((float*)Cout + idx, tmp, 16);
      }
    }
  }
}

// ---------------- 128x128 BK=32 bf16 GEMM (round-1 skeleton; Q & out-proj) ---
template <bool RELU, bool OUT_BF16>
__global__ __launch_bounds__(256, 2) void gemm_bt(
    const bf16* __restrict__ A, const bf16* __restrict__ Bt, void* __restrict__ Cout,
    const float* __restrict__ bias, int M, int N, int K, int lda, int ldb, int ldc,
    long abs_, long bbs, long cbs, long biasbs, const int* __restrict__ eid,
    int eid_scale) {
  int e = blockIdx.z;
  A    += (long)e * abs_;
  Bt   += (long)e * bbs;
  bias += (long)e * biasbs;
  long coff = (long)e * cbs;
  if (eid) A += (long)(*eid) * eid_scale;

  __shared__ bf16 As[128 * 32];
  __shared__ bf16 Bs[128 * 32];

  int tid = threadIdx.x;
  int wave = tid >> 6, lane = tid & 63;
  int wm = wave >> 1, wn = wave & 1;
  int bm = blockIdx.x * 128, bn = blockIdx.y * 128;

  int srow  = lane >> 2;
  int skoff = (lane & 3) * 8;

  f32x4 acc[4][4] = {};

  const bf16* Abase = A + (long)bm * lda;
  const bf16* Bbase = Bt + (long)bn * ldb;

  for (int k0 = 0; k0 < K; k0 += 32) {
    __syncthreads();
#pragma unroll
    for (int i = 0; i < 2; i++) {
      int r = wave * 32 + i * 16 + srow;
      GL16(Abase + (long)r * lda + k0 + skoff, As + (wave * 32 + i * 16) * 32);
      GL16(Bbase + (long)r * ldb + k0 + skoff, Bs + (wave * 32 + i * 16) * 32);
    }
    __syncthreads();

    s16x8 af[4], bfr[4];
#pragma unroll
    for (int m = 0; m < 4; m++)
      af[m] = *reinterpret_cast<const s16x8*>(As + (wm * 64 + m * 16 + (lane & 15)) * 32 +
                                              (lane >> 4) * 8);
#pragma unroll
    for (int n = 0; n < 4; n++)
      bfr[n] = *reinterpret_cast<const s16x8*>(Bs + (wn * 64 + n * 16 + (lane & 15)) * 32 +
                                               (lane >> 4) * 8);
#pragma unroll
    for (int m = 0; m < 4; m++)
#pragma unroll
      for (int n = 0; n < 4; n++)
        acc[m][n] = __builtin_amdgcn_mfma_f32_16x16x32_bf16(af[m], bfr[n], acc[m][n], 0, 0, 0);
  }

  int cr = (lane >> 4) * 4, cc = lane & 15;
#pragma unroll
  for (int m = 0; m < 4; m++) {
#pragma unroll
    for (int n = 0; n < 4; n++) {
      int col  = bn + wn * 64 + n * 16 + cc;
      float bv = bias ? bias[col] : 0.0f;
#pragma unroll
      for (int r = 0; r < 4; r++) {
        int row = bm + wm * 64 + m * 16 + cr + r;
        float v = acc[m][n][r] + bv;
        if (RELU) v = fmaxf(v, 0.0f);
        long idx = coff + (long)row * ldc + col;
        if (OUT_BF16)
          ((bf16*)Cout)[idx] = f2bf(v);
        else
          ((float*)Cout)[idx] = v;
      }
    }
  }
}

// ---------------- attention over the expert axis (E=8, H=8, HD=64) ----------
__global__ __launch_bounds__(256) void attn_kernel(const float* __restrict__ q,
                                                   const bf16* __restrict__ kv,
                                                   bf16* __restrict__ ctx,
                                                   const int* __restrict__ eid) {
  int wave = threadIdx.x >> 6, lane = threadIdx.x & 63;
  int n = blockIdx.x * 4 + wave;
  int h = lane >> 3, f = lane & 7;
  int e3 = *eid;
  const bf16* kvn = kv + (long)n * Em * (2 * Dm);
  const float* qh = q + (long)n * Dm + h * 64;
  const bf16* kf = kvn + f * (2 * Dm) + h * 64;
  float s = 0.f;
#pragma unroll
  for (int j = 0; j < 64; j++) s += qh[j] * bf2f(kf[j]);
  s *= 0.125f;
  s += (f <= e3) ? 1.0f : 0.0f;  // torch-faithful ADDITIVE float tril mask
  float mx = s;
#pragma unroll
  for (int d = 1; d < 8; d <<= 1) mx = fmaxf(mx, __shfl_xor(mx, d));
  float ex = expf(s - mx);
  float sm = ex;
#pragma unroll
  for (int d = 1; d < 8; d <<= 1) sm += __shfl_xor(sm, d);
  float at = ex / sm;
  int g = f;
  float acc[8] = {0, 0, 0, 0, 0, 0, 0, 0};
#pragma unroll
  for (int f2 = 0; f2 < 8; f2++) {
    float a = __shfl(at, (h << 3) | f2);
    const bf16* vf = kvn + f2 * (2 * Dm) + Dm + h * 64 + g * 8;
#pragma unroll
    for (int j = 0; j < 8; j++) acc[j] += a * bf2f(vf[j]);
  }
  bf16 tmp[8];
#pragma unroll
  for (int j = 0; j < 8; j++) tmp[j] = f2bf(acc[j]);
  __builtin_memcpy(ctx + (long)n * Dm + h * 64 + g * 8, tmp, 16);
}

extern "C" void kernel_launch(void* const* d_in, const int* in_sizes, int n_in,
                              void* d_out, int out_size, void* d_ws, size_t ws_size,
                              hipStream_t stream) {
  const float* x  = (const float*)d_in[0];
  const float* W1 = (const float*)d_in[1];
  const float* b1 = (const float*)d_in[2];
  const float* W2 = (const float*)d_in[3];
  const float* b2 = (const float*)d_in[4];
  const float* Wq = (const float*)d_in[5];
  const float* bq = (const float*)d_in[6];
  const float* Wk = (const float*)d_in[7];
  const float* bk = (const float*)d_in[8];
  const float* Wv = (const float*)d_in[9];
  const float* bv = (const float*)d_in[10];
  const float* Wo = (const float*)d_in[11];
  const float* bo = (const float*)d_in[12];
  const int* eid  = (const int*)d_in[13];

  char* w = (char*)d_ws;
  auto alloc = [&](size_t bytes) {
    char* p = w;
    w += (bytes + 255) & ~(size_t)255;
    return p;
  };
  bf16* xb   = (bf16*)alloc((size_t)N_TOK * Dm * 2);
  bf16* W1t  = (bf16*)alloc((size_t)Em * Fm * Dm * 2);
  bf16* W2t  = (bf16*)alloc((size_t)Em * Dm * Fm * 2);
  bf16* qw   = (bf16*)alloc((size_t)Dm * Dm * 2);
  bf16* kvw  = (bf16*)alloc((size_t)2 * Dm * Dm * 2);
  bf16* ow   = (bf16*)alloc((size_t)Dm * Dm * 2);
  float* bkv = (float*)alloc((size_t)2 * Dm * 4);
  bf16* hid  = (bf16*)alloc((size_t)Em * N_TOK * Fm * 2);   // 128 MB [e][n][f]
  bf16* eo   = (bf16*)alloc((size_t)N_TOK * Em * Dm * 2);   // [n][e][d]
  bf16* kv   = (bf16*)hid;                                  // alias: [n*E+e][2D]
  float* qb  = (float*)(hid + (size_t)N_TOK * Em * 2 * Dm);
  bf16* ctxb = (bf16*)(qb + (size_t)N_TOK * Dm);

  // allow 96 KB dynamic LDS on the big GEMM instantiations
  hipFuncSetAttribute(reinterpret_cast<const void*>(gemm3p<true, true>),
                      hipFuncAttributeMaxDynamicSharedMemorySize, 98304);
  hipFuncSetAttribute(reinterpret_cast<const void*>(gemm3p<false, true>),
                      hipFuncAttributeMaxDynamicSharedMemorySize, 98304);

  // ---- converts / transposes ----
  cvt_f32_bf16<<<(N_TOK * Dm / 4 + 255) / 256, 256, 0, stream>>>(x, xb, N_TOK * Dm / 4);
  transpose_cvt<<<dim3(Fm / 32, Dm / 32, Em), 256, 0, stream>>>(
      W1, W1t, Dm, Fm, (long)Dm * Fm, (long)Fm * Dm);
  transpose_cvt<<<dim3(Dm / 32, Fm / 32, Em), 256, 0, stream>>>(
      W2, W2t, Fm, Dm, (long)Fm * Dm, (long)Dm * Fm);
  int nw4 = Dm * Dm / 4;
  cvt_f32_bf16<<<(nw4 + 255) / 256, 256, 0, stream>>>(Wq, qw, nw4);
  cvt_f32_bf16<<<(nw4 + 255) / 256, 256, 0, stream>>>(Wk, kvw, nw4);
  cvt_f32_bf16<<<(nw4 + 255) / 256, 256, 0, stream>>>(Wv, kvw + (size_t)Dm * Dm, nw4);
  cvt_f32_bf16<<<(nw4 + 255) / 256, 256, 0, stream>>>(Wo, ow, nw4);
  hipMemcpyAsync(bkv, bk, Dm * sizeof(float), hipMemcpyDeviceToDevice, stream);
  hipMemcpyAsync(bkv + Dm, bv, Dm * sizeof(float), hipMemcpyDeviceToDevice, stream);

  // ---- FFN stage 1: hid[e] = relu(x @ W1[e] + b1[e])  M=4096 N=2048 K=512
  gemm3p<true, true><<<dim3(16, 8, Em), 512, 98304, stream>>>(
      xb, W1t, hid, b1, Dm, Dm, Dm, Fm,
      0L, (long)Fm * Dm, (long)N_TOK * Fm, (long)Fm);
  // ---- FFN stage 2: eo[n][e][:] = hid[e] @ W2[e] + b2[e]  M=4096 N=512 K=2048
  gemm3p<false, true><<<dim3(16, 2, Em), 512, 98304, stream>>>(
      hid, W2t, eo, b2, Fm, Fm, Fm, Em * Dm,
      (long)N_TOK * Fm, (long)Dm * Fm, (long)Dm, (long)Dm);
  // ---- K|V for all expert rows: M=32768 N=1024 K=512
  gemm3p<false, true><<<dim3(128, 4, 1), 512, 98304, stream>>>(
      eo, kvw, kv, bkv, Dm, Dm, Dm, 2 * Dm,
      0L, 0L, 0L, 0L);
  // ---- Q only for expert row e_id (small: 128^2 kernel)
  gemm_bt<false, false><<<dim3(N_TOK / 128, Dm / 128, 1), 256, 0, stream>>>(
      eo, qw, qb, bq, N_TOK, Dm, Dm, Em * Dm, Dm, Dm,
      0L, 0L, 0L, 0L, eid, Dm);
  // ---- attention over experts ----
  attn_kernel<<<N_TOK / 4, 256, 0, stream>>>(qb, kv, ctxb, eid);
  // ---- out projection -> d_out (fp32) ----
  gemm_bt<false, false><<<dim3(N_TOK / 128, Dm / 128, 1), 256, 0, stream>>>(
      ctxb, ow, (float*)d_out, bo, N_TOK, Dm, Dm, Dm, Dm, Dm,
      0L, 0L, 0L, 0L, nullptr, 0);
}

// Round 13
// 314.165 us; speedup vs baseline: 4.4267x; 4.4267x over previous
//
#include <hip/hip_runtime.h>
#include <hip/hip_bf16.h>

typedef __hip_bfloat16 bf16;
typedef __attribute__((ext_vector_type(4))) float f32x4;
typedef __attribute__((ext_vector_type(8))) short s16x8;

#define N_TOK 4096   // B*S
#define Dm    512
#define Fm    2048
#define Em    8

__device__ __forceinline__ float bf2f(bf16 v) { return __bfloat162float(v); }
__device__ __forceinline__ bf16  f2bf(float f) { return __float2bfloat16(f); }

// async global->LDS, 16B per lane; LDS dest is wave-uniform base + lane*16
#define GL16(g, l)                                                              \
  __builtin_amdgcn_global_load_lds(                                             \
      (const __attribute__((address_space(1))) void*)(g),                       \
      (__attribute__((address_space(3))) void*)(l), 16, 0, 0)

#define BAR()                                   \
  do {                                          \
    __builtin_amdgcn_s_barrier();               \
    asm volatile("" ::: "memory");              \
  } while (0)

// ---------------- fp32 -> bf16 flat convert ----------------------------------
__global__ void cvt_f32_bf16(const float* __restrict__ in, bf16* __restrict__ out, int n4) {
  int i = blockIdx.x * 256 + threadIdx.x;
  if (i >= n4) return;
  float4 v = reinterpret_cast<const float4*>(in)[i];
  bf16 tmp[4] = {f2bf(v.x), f2bf(v.y), f2bf(v.z), f2bf(v.w)};
  __builtin_memcpy(out + (size_t)i * 4, tmp, 8);
}

// ---------------- fp32 [R][C] -> bf16 [C][R] tiled transpose-convert ---------
__global__ void transpose_cvt(const float* __restrict__ in, bf16* __restrict__ out,
                              int R, int C, long inb, long outb) {
  in  += (long)blockIdx.z * inb;
  out += (long)blockIdx.z * outb;
  __shared__ float t[32][33];
  int tx = threadIdx.x & 31, ty = threadIdx.x >> 5;
  int c0 = blockIdx.x * 32, r0 = blockIdx.y * 32;
#pragma unroll
  for (int i = 0; i < 32; i += 8)
    t[ty + i][tx] = in[(long)(r0 + ty + i) * C + c0 + tx];
  __syncthreads();
#pragma unroll
  for (int i = 0; i < 32; i += 8)
    out[(long)(c0 + ty + i) * R + r0 + tx] = f2bf(t[tx][ty + i]);
}

// ====== 256x256 BK=32 bf16 GEMM, 3-buffer 2-tile-deep pipeline (r13) =========
// r12 POST-MORTEM: identical kernel but missing __launch_bounds__ -> compiler
// capped VGPR at 64 -> acc[8][4] spilled to scratch (WRITE_SIZE 1.7 GB,
// MfmaUtil 5%). r13 restores __launch_bounds__(512,2) (r8 compiled clean at
// 112 VGPR with it). Schedule unchanged & audited:
//   - prologue: stage tiles 0,1 (8 loads/thread in flight)
//   - top of tile t: vmcnt(4) retires exactly tile t's 4 loads; ONE barrier
//   - phases 1/2 issue stageA/stageB(t+2) (wait-to-issue = 2 tiles ~ >600cy)
//   - buffer reuse safe: stage(t+2) only after barrier(t) => all waves done
//     reading buf((t-1)%3) == buf((t+2)%3)
//   - NO sched_barrier (m141: order-pinning −40%)
// Swizzle both sides (#21): global source chunk = (tid&3) ^ ((srow>>1)&3),
// LDS dest linear; ds_read phys slot = q ^ ((r>>1)&3) -> 2-way max (free).
// Swapped MFMA operands: acc[m][n][r] ->
// C[bm+wm*128+(m>>2)*64+(m&3)*16+la][bn+wn*64+n*16+q*4+r], packed stores.
template <bool RELU, bool OUT_BF16>
__global__ __launch_bounds__(512, 2) void gemm3p(
    const bf16* __restrict__ A, const bf16* __restrict__ Bt, void* __restrict__ Cout,
    const float* __restrict__ bias, int K, int lda, int ldb, int ldc,
    long abs_, long bbs, long cbs, long biasbs) {
  extern __shared__ bf16 lds[];  // 3 bufs x (8192 A + 8192 B) bf16 = 96 KB

  int e  = blockIdx.z;
  int bm = blockIdx.x * 256, bn = blockIdx.y * 256;

  A    += (long)e * abs_;
  Bt   += (long)e * bbs;
  bias += (long)e * biasbs;
  long coff = (long)e * cbs;

  int tid = threadIdx.x, wv = tid >> 6, lane = tid & 63;
  int wm = wv >> 2, wn = wv & 3;  // 2x4 wave grid, 128x64 per wave
  int la = lane & 15, q = lane >> 4;

  const bf16* Ab = A + (long)bm * lda;
  const bf16* Bb = Bt + (long)bn * ldb;
  int nt = K >> 5;  // BK = 32

  int srow = tid >> 2;
  int ls   = (tid & 3) ^ ((srow >> 1) & 3);
  long aoff0 = (long)srow * lda + ls * 8, aoff1 = aoff0 + (long)128 * lda;
  long boff0 = (long)srow * ldb + ls * 8, boff1 = boff0 + (long)128 * ldb;
  int dst0 = (wv * 64) * 8, dst1 = (512 + wv * 64) * 8;  // wave-uniform bases

  auto stageA = [&](int t) {
    if (t >= nt) return;
    bf16* buf = lds + (t % 3) * 16384;
    int k0 = t << 5;
    GL16(Ab + aoff0 + k0, buf + dst0);
    GL16(Ab + aoff1 + k0, buf + dst1);
  };
  auto stageB = [&](int t) {
    if (t >= nt) return;
    bf16* buf = lds + (t % 3) * 16384 + 8192;
    int k0 = t << 5;
    GL16(Bb + boff0 + k0, buf + dst0);
    GL16(Bb + boff1 + k0, buf + dst1);
  };

  f32x4 acc[8][4] = {};
  s16x8 af[4], bfr[4];

  // prologue: tiles 0 and 1 fully in flight (8 loads/thread outstanding)
  stageA(0); stageB(0);
  stageA(1); stageB(1);

  for (int t = 0; t < nt; ++t) {
    if (t + 1 < nt) asm volatile("s_waitcnt vmcnt(4)" ::: "memory");
    else            asm volatile("s_waitcnt vmcnt(0)" ::: "memory");
    BAR();  // all waves' tile-t loads retired & visible
    const bf16* Abuf = lds + (t % 3) * 16384;
    const bf16* Bbuf = Abuf + 8192;
    // ---- phase 1: m-half 0 ----
#pragma unroll
    for (int m = 0; m < 4; ++m) {
      int r = wm * 128 + m * 16 + la;
      af[m] = *reinterpret_cast<const s16x8*>(Abuf + r * 32 + ((q ^ ((r >> 1) & 3)) * 8));
    }
#pragma unroll
    for (int n = 0; n < 4; ++n) {
      int r = wn * 64 + n * 16 + la;
      bfr[n] = *reinterpret_cast<const s16x8*>(Bbuf + r * 32 + ((q ^ ((r >> 1) & 3)) * 8));
    }
    stageA(t + 2);
    __builtin_amdgcn_s_setprio(1);
#pragma unroll
    for (int m = 0; m < 4; ++m)
#pragma unroll
      for (int n = 0; n < 4; ++n)
        acc[m][n] = __builtin_amdgcn_mfma_f32_16x16x32_bf16(bfr[n], af[m], acc[m][n], 0, 0, 0);
    __builtin_amdgcn_s_setprio(0);
    // ---- phase 2: m-half 1 (B frags reused from registers) ----
#pragma unroll
    for (int m = 0; m < 4; ++m) {
      int r = wm * 128 + 64 + m * 16 + la;
      af[m] = *reinterpret_cast<const s16x8*>(Abuf + r * 32 + ((q ^ ((r >> 1) & 3)) * 8));
    }
    stageB(t + 2);
    __builtin_amdgcn_s_setprio(1);
#pragma unroll
    for (int m = 0; m < 4; ++m)
#pragma unroll
      for (int n = 0; n < 4; ++n)
        acc[4 + m][n] = __builtin_amdgcn_mfma_f32_16x16x32_bf16(bfr[n], af[m], acc[4 + m][n], 0, 0, 0);
    __builtin_amdgcn_s_setprio(0);
  }

  // epilogue
#pragma unroll
  for (int m = 0; m < 8; ++m) {
    int gm = bm + wm * 128 + (m >> 2) * 64 + (m & 3) * 16 + la;
#pragma unroll
    for (int n = 0; n < 4; ++n) {
      int gn = bn + wn * 64 + n * 16 + q * 4;
      float4 b4 = *reinterpret_cast<const float4*>(bias + gn);
      float v0 = acc[m][n][0] + b4.x, v1 = acc[m][n][1] + b4.y;
      float v2 = acc[m][n][2] + b4.z, v3 = acc[m][n][3] + b4.w;
      if (RELU) {
        v0 = fmaxf(v0, 0.f); v1 = fmaxf(v1, 0.f);
        v2 = fmaxf(v2, 0.f); v3 = fmaxf(v3, 0.f);
      }
      long idx = coff + (long)gm * ldc + gn;
      if (OUT_BF16) {
        bf16 tmp[4] = {f2bf(v0), f2bf(v1), f2bf(v2), f2bf(v3)};
        __builtin_memcpy((bf16*)Cout + idx, tmp, 8);
      } else {
        float tmp[4] = {v0, v1, v2, v3};
        __builtin_memcpy((float*)Cout + idx, tmp, 16);
      }
    }
  }
}

// ---------------- 128x128 BK=32 bf16 GEMM (round-1 skeleton; Q & out-proj) ---
template <bool RELU, bool OUT_BF16>
__global__ __launch_bounds__(256, 2) void gemm_bt(
    const bf16* __restrict__ A, const bf16* __restrict__ Bt, void* __restrict__ Cout,
    const float* __restrict__ bias, int M, int N, int K, int lda, int ldb, int ldc,
    long abs_, long bbs, long cbs, long biasbs, const int* __restrict__ eid,
    int eid_scale) {
  int e = blockIdx.z;
  A    += (long)e * abs_;
  Bt   += (long)e * bbs;
  bias += (long)e * biasbs;
  long coff = (long)e * cbs;
  if (eid) A += (long)(*eid) * eid_scale;

  __shared__ bf16 As[128 * 32];
  __shared__ bf16 Bs[128 * 32];

  int tid = threadIdx.x;
  int wave = tid >> 6, lane = tid & 63;
  int wm = wave >> 1, wn = wave & 1;
  int bm = blockIdx.x * 128, bn = blockIdx.y * 128;

  int srow  = lane >> 2;
  int skoff = (lane & 3) * 8;

  f32x4 acc[4][4] = {};

  const bf16* Abase = A + (long)bm * lda;
  const bf16* Bbase = Bt + (long)bn * ldb;

  for (int k0 = 0; k0 < K; k0 += 32) {
    __syncthreads();
#pragma unroll
    for (int i = 0; i < 2; i++) {
      int r = wave * 32 + i * 16 + srow;
      GL16(Abase + (long)r * lda + k0 + skoff, As + (wave * 32 + i * 16) * 32);
      GL16(Bbase + (long)r * ldb + k0 + skoff, Bs + (wave * 32 + i * 16) * 32);
    }
    __syncthreads();

    s16x8 af[4], bfr[4];
#pragma unroll
    for (int m = 0; m < 4; m++)
      af[m] = *reinterpret_cast<const s16x8*>(As + (wm * 64 + m * 16 + (lane & 15)) * 32 +
                                              (lane >> 4) * 8);
#pragma unroll
    for (int n = 0; n < 4; n++)
      bfr[n] = *reinterpret_cast<const s16x8*>(Bs + (wn * 64 + n * 16 + (lane & 15)) * 32 +
                                               (lane >> 4) * 8);
#pragma unroll
    for (int m = 0; m < 4; m++)
#pragma unroll
      for (int n = 0; n < 4; n++)
        acc[m][n] = __builtin_amdgcn_mfma_f32_16x16x32_bf16(af[m], bfr[n], acc[m][n], 0, 0, 0);
  }

  int cr = (lane >> 4) * 4, cc = lane & 15;
#pragma unroll
  for (int m = 0; m < 4; m++) {
#pragma unroll
    for (int n = 0; n < 4; n++) {
      int col  = bn + wn * 64 + n * 16 + cc;
      float bv = bias ? bias[col] : 0.0f;
#pragma unroll
      for (int r = 0; r < 4; r++) {
        int row = bm + wm * 64 + m * 16 + cr + r;
        float v = acc[m][n][r] + bv;
        if (RELU) v = fmaxf(v, 0.0f);
        long idx = coff + (long)row * ldc + col;
        if (OUT_BF16)
          ((bf16*)Cout)[idx] = f2bf(v);
        else
          ((float*)Cout)[idx] = v;
      }
    }
  }
}

// ---------------- attention over the expert axis (E=8, H=8, HD=64) ----------
__global__ __launch_bounds__(256) void attn_kernel(const float* __restrict__ q,
                                                   const bf16* __restrict__ kv,
                                                   bf16* __restrict__ ctx,
                                                   const int* __restrict__ eid) {
  int wave = threadIdx.x >> 6, lane = threadIdx.x & 63;
  int n = blockIdx.x * 4 + wave;
  int h = lane >> 3, f = lane & 7;
  int e3 = *eid;
  const bf16* kvn = kv + (long)n * Em * (2 * Dm);
  const float* qh = q + (long)n * Dm + h * 64;
  const bf16* kf = kvn + f * (2 * Dm) + h * 64;
  float s = 0.f;
#pragma unroll
  for (int j = 0; j < 64; j++) s += qh[j] * bf2f(kf[j]);
  s *= 0.125f;
  s += (f <= e3) ? 1.0f : 0.0f;  // torch-faithful ADDITIVE float tril mask
  float mx = s;
#pragma unroll
  for (int d = 1; d < 8; d <<= 1) mx = fmaxf(mx, __shfl_xor(mx, d));
  float ex = expf(s - mx);
  float sm = ex;
#pragma unroll
  for (int d = 1; d < 8; d <<= 1) sm += __shfl_xor(sm, d);
  float at = ex / sm;
  int g = f;
  float acc[8] = {0, 0, 0, 0, 0, 0, 0, 0};
#pragma unroll
  for (int f2 = 0; f2 < 8; f2++) {
    float a = __shfl(at, (h << 3) | f2);
    const bf16* vf = kvn + f2 * (2 * Dm) + Dm + h * 64 + g * 8;
#pragma unroll
    for (int j = 0; j < 8; j++) acc[j] += a * bf2f(vf[j]);
  }
  bf16 tmp[8];
#pragma unroll
  for (int j = 0; j < 8; j++) tmp[j] = f2bf(acc[j]);
  __builtin_memcpy(ctx + (long)n * Dm + h * 64 + g * 8, tmp, 16);
}

extern "C" void kernel_launch(void* const* d_in, const int* in_sizes, int n_in,
                              void* d_out, int out_size, void* d_ws, size_t ws_size,
                              hipStream_t stream) {
  const float* x  = (const float*)d_in[0];
  const float* W1 = (const float*)d_in[1];
  const float* b1 = (const float*)d_in[2];
  const float* W2 = (const float*)d_in[3];
  const float* b2 = (const float*)d_in[4];
  const float* Wq = (const float*)d_in[5];
  const float* bq = (const float*)d_in[6];
  const float* Wk = (const float*)d_in[7];
  const float* bk = (const float*)d_in[8];
  const float* Wv = (const float*)d_in[9];
  const float* bv = (const float*)d_in[10];
  const float* Wo = (const float*)d_in[11];
  const float* bo = (const float*)d_in[12];
  const int* eid  = (const int*)d_in[13];

  char* w = (char*)d_ws;
  auto alloc = [&](size_t bytes) {
    char* p = w;
    w += (bytes + 255) & ~(size_t)255;
    return p;
  };
  bf16* xb   = (bf16*)alloc((size_t)N_TOK * Dm * 2);
  bf16* W1t  = (bf16*)alloc((size_t)Em * Fm * Dm * 2);
  bf16* W2t  = (bf16*)alloc((size_t)Em * Dm * Fm * 2);
  bf16* qw   = (bf16*)alloc((size_t)Dm * Dm * 2);
  bf16* kvw  = (bf16*)alloc((size_t)2 * Dm * Dm * 2);
  bf16* ow   = (bf16*)alloc((size_t)Dm * Dm * 2);
  float* bkv = (float*)alloc((size_t)2 * Dm * 4);
  bf16* hid  = (bf16*)alloc((size_t)Em * N_TOK * Fm * 2);   // 128 MB [e][n][f]
  bf16* eo   = (bf16*)alloc((size_t)N_TOK * Em * Dm * 2);   // [n][e][d]
  bf16* kv   = (bf16*)hid;                                  // alias: [n*E+e][2D]
  float* qb  = (float*)(hid + (size_t)N_TOK * Em * 2 * Dm);
  bf16* ctxb = (bf16*)(qb + (size_t)N_TOK * Dm);

  // allow 96 KB dynamic LDS on the big GEMM instantiations
  hipFuncSetAttribute(reinterpret_cast<const void*>(gemm3p<true, true>),
                      hipFuncAttributeMaxDynamicSharedMemorySize, 98304);
  hipFuncSetAttribute(reinterpret_cast<const void*>(gemm3p<false, true>),
                      hipFuncAttributeMaxDynamicSharedMemorySize, 98304);

  // ---- converts / transposes ----
  cvt_f32_bf16<<<(N_TOK * Dm / 4 + 255) / 256, 256, 0, stream>>>(x, xb, N_TOK * Dm / 4);
  transpose_cvt<<<dim3(Fm / 32, Dm / 32, Em), 256, 0, stream>>>(
      W1, W1t, Dm, Fm, (long)Dm * Fm, (long)Fm * Dm);
  transpose_cvt<<<dim3(Dm / 32, Fm / 32, Em), 256, 0, stream>>>(
      W2, W2t, Fm, Dm, (long)Fm * Dm, (long)Dm * Fm);
  int nw4 = Dm * Dm / 4;
  cvt_f32_bf16<<<(nw4 + 255) / 256, 256, 0, stream>>>(Wq, qw, nw4);
  cvt_f32_bf16<<<(nw4 + 255) / 256, 256, 0, stream>>>(Wk, kvw, nw4);
  cvt_f32_bf16<<<(nw4 + 255) / 256, 256, 0, stream>>>(Wv, kvw + (size_t)Dm * Dm, nw4);
  cvt_f32_bf16<<<(nw4 + 255) / 256, 256, 0, stream>>>(Wo, ow, nw4);
  hipMemcpyAsync(bkv, bk, Dm * sizeof(float), hipMemcpyDeviceToDevice, stream);
  hipMemcpyAsync(bkv + Dm, bv, Dm * sizeof(float), hipMemcpyDeviceToDevice, stream);

  // ---- FFN stage 1: hid[e] = relu(x @ W1[e] + b1[e])  M=4096 N=2048 K=512
  gemm3p<true, true><<<dim3(16, 8, Em), 512, 98304, stream>>>(
      xb, W1t, hid, b1, Dm, Dm, Dm, Fm,
      0L, (long)Fm * Dm, (long)N_TOK * Fm, (long)Fm);
  // ---- FFN stage 2: eo[n][e][:] = hid[e] @ W2[e] + b2[e]  M=4096 N=512 K=2048
  gemm3p<false, true><<<dim3(16, 2, Em), 512, 98304, stream>>>(
      hid, W2t, eo, b2, Fm, Fm, Fm, Em * Dm,
      (long)N_TOK * Fm, (long)Dm * Fm, (long)Dm, (long)Dm);
  // ---- K|V for all expert rows: M=32768 N=1024 K=512
  gemm3p<false, true><<<dim3(128, 4, 1), 512, 98304, stream>>>(
      eo, kvw, kv, bkv, Dm, Dm, Dm, 2 * Dm,
      0L, 0L, 0L, 0L);
  // ---- Q only for expert row e_id (small: 128^2 kernel)
  gemm_bt<false, false><<<dim3(N_TOK / 128, Dm / 128, 1), 256, 0, stream>>>(
      eo, qw, qb, bq, N_TOK, Dm, Dm, Em * Dm, Dm, Dm,
      0L, 0L, 0L, 0L, eid, Dm);
  // ---- attention over experts ----
  attn_kernel<<<N_TOK / 4, 256, 0, stream>>>(qb, kv, ctxb, eid);
  // ---- out projection -> d_out (fp32) ----
  gemm_bt<false, false><<<dim3(N_TOK / 128, Dm / 128, 1), 256, 0, stream>>>(
      ctxb, ow, (float*)d_out, bo, N_TOK, Dm, Dm, Dm, Dm, Dm,
      0L, 0L, 0L, 0L, nullptr, 0);
}